// Round 6
// baseline (6030.695 us; speedup 1.0000x reference)
//
#include <hip/hip_runtime.h>
#include <stdint.h>

#define TSTEPS 512

typedef __attribute__((ext_vector_type(8))) _Float16 half8;
typedef __attribute__((ext_vector_type(4))) _Float16 half4;
typedef __attribute__((ext_vector_type(2))) _Float16 half2v;
typedef __attribute__((ext_vector_type(4))) float f32x4;
typedef __attribute__((ext_vector_type(4))) float float4v;
typedef __attribute__((ext_vector_type(4))) int i32x4;
typedef unsigned long long u64;

static __device__ __forceinline__ float sigm(float x) { return 1.f / (1.f + __expf(-x)); }
static __device__ __forceinline__ float tanh_(float x) {
  x = fminf(15.f, fmaxf(-15.f, x));
  float e = __expf(-2.f * x);
  return (1.f - e) / (1.f + e);
}
static __device__ __forceinline__ half8 ld8(const _Float16* p) { return *(const half8*)p; }
static __device__ __forceinline__ f32x4 MFMA(half8 a, half8 b, f32x4 c) {
  return __builtin_amdgcn_mfma_f32_16x16x32_f16(a, b, c, 0, 0, 0);
}

// ---- self-validating messages through the MALL (proven relaxed agent atomics).
// msg u64 = { lo32: half2 data, hi32: step tag }. u64 single-copy atomicity
// guarantees tag==t  =>  data is step t's. No fences, no flags, no barriers.
static __device__ __forceinline__ u64 ld_msg(const u64* p) {
  return __hip_atomic_load(p, __ATOMIC_RELAXED, __HIP_MEMORY_SCOPE_AGENT);
}
static __device__ __forceinline__ void st_msg(u64* p, u64 v) {
  __hip_atomic_store(p, v, __ATOMIC_RELAXED, __HIP_MEMORY_SCOPE_AGENT);
}

// ---------------- f32 -> f16 conversion / msg-buffer init ----------------
__global__ __launch_bounds__(256) void kconv(
    const float* __restrict__ xs, const float* __restrict__ wih,
    const float* __restrict__ wxh, const float* __restrict__ whhf,
    const float* __restrict__ wrf, const float* __restrict__ h0,
    _Float16* __restrict__ xs_h, _Float16* __restrict__ wcat,
    _Float16* __restrict__ whh, _Float16* __restrict__ wr,
    u64* __restrict__ hmsg, u64* __restrict__ rhmsg) {
  const long n1 = 8388608;   // xs / 4
  const long n2 = 1048576;   // wcat / 4
  const long n3 = 786432;    // whh / 4
  const long n4 = 262144;    // wr / 4
  const long b4 = n1 + n2 + n3 + n4;
  const long n5 = 32768;     // hmsg u64 count (4 grp x 16 row x 512 pair)
  const long n6 = 32768;     // rhmsg u64 count
  const long total = b4 + n5 + n6;
  for (long i = (long)blockIdx.x * 256 + threadIdx.x; i < total; i += (long)gridDim.x * 256) {
    if (i < b4) {
      const float* s; _Float16* d;
      if (i < n1) { s = xs + i * 4; d = xs_h + i * 4; }
      else if (i < n1 + n2) {
        long e = (i - n1) * 4;
        s = (e < 3145728) ? (wih + e) : (wxh + (e - 3145728));
        d = wcat + e;
      } else if (i < n1 + n2 + n3) { long e = (i - n1 - n2) * 4; s = whhf + e; d = whh + e; }
      else { long e = (i - n1 - n2 - n3) * 4; s = wrf + e; d = wr + e; }
      float4v v = *(const float4v*)s;
      half4 o = { (_Float16)v.x, (_Float16)v.y, (_Float16)v.z, (_Float16)v.w };
      *(half4*)d = o;
    } else if (i < b4 + n5) {
      // hmsg: h0 data, tag 0  (replay-safe full reset)
      long e = i - b4;
      int g = (int)(e >> 13), rem = (int)(e & 8191);
      int row = rem >> 9, pr = rem & 511;
      const float* hp = h0 + (size_t)(g * 16 + row) * 1024 + 2 * pr;
      half2v h2 = { (_Float16)hp[0], (_Float16)hp[1] };
      hmsg[e] = (u64)(unsigned)__builtin_bit_cast(unsigned, h2);
    } else {
      // rhmsg: sentinel tag (never matches any expected tag 1..512)
      rhmsg[i - b4 - n5] = 0xFFFFFFFF00000000ull;
    }
  }
}

// ---------------- big input-side GEMM: xgh[32768][4096] = xs @ [W_ih;W_xh]^T + bias ----------------
__global__ __launch_bounds__(256) void kgemm(
    const _Float16* __restrict__ X, const _Float16* __restrict__ W,
    const float* __restrict__ b_ih, const float* __restrict__ b_xh,
    _Float16* __restrict__ C) {
  __shared__ _Float16 As[128 * 40], Bs[128 * 40];
  const int tid = threadIdx.x;
  const int lane = tid & 63;
  const int w = tid >> 6;
  const int wm = (w >> 1) * 64, wn = (w & 1) * 64;
  const int bn = blockIdx.x * 128;
  const int bm = blockIdx.y * 128;
  const int arow = tid >> 2;
  const int kk8 = (tid & 3) * 8;
  const int fr = lane & 15, fq = lane >> 4;
  const f32x4 zero = {0.f, 0.f, 0.f, 0.f};
  f32x4 acc[4][4];
  #pragma unroll
  for (int a = 0; a < 4; a++)
    #pragma unroll
    for (int b = 0; b < 4; b++) acc[a][b] = zero;
  for (int kt = 0; kt < 1024; kt += 32) {
    __syncthreads();
    #pragma unroll
    for (int j = 0; j < 2; j++) {
      int r = j * 64 + arow;
      *(half8*)(As + r * 40 + kk8) = ld8(X + (size_t)(bm + r) * 1024 + kt + kk8);
      *(half8*)(Bs + r * 40 + kk8) = ld8(W + (size_t)(bn + r) * 1024 + kt + kk8);
    }
    __syncthreads();
    half8 af[4], bfr[4];
    #pragma unroll
    for (int i = 0; i < 4; i++) {
      af[i]  = *(const half8*)(As + (wm + i * 16 + fr) * 40 + fq * 8);
      bfr[i] = *(const half8*)(Bs + (wn + i * 16 + fr) * 40 + fq * 8);
    }
    #pragma unroll
    for (int mi = 0; mi < 4; mi++)
      #pragma unroll
      for (int ni = 0; ni < 4; ni++)
        acc[mi][ni] = MFMA(af[mi], bfr[ni], acc[mi][ni]);
  }
  #pragma unroll
  for (int mi = 0; mi < 4; mi++)
    #pragma unroll
    for (int ni = 0; ni < 4; ni++) {
      int col = bn + wn + ni * 16 + fr;
      float bias = (col < 3072) ? b_ih[col] : b_xh[col - 3072];
      #pragma unroll
      for (int r = 0; r < 4; r++) {
        int row = bm + wm + mi * 16 + fq * 4 + r;
        C[(size_t)row * 4096 + col] = (_Float16)(acc[mi][ni][r] + bias);
      }
    }
}

// ---------------- persistent recurrent kernel ----------------
// 4 groups x 32 wgs x 512 thr. Group owns 16 batch rows; wg owns 32 h-cols.
// Wave w holds K-slice [128w,128w+128) of W_hh/W_r; split-K reduced in LDS.
// Cross-wg h/rh exchange: tagged u64 msgs through the MALL; consumers poll
// the data directly (no flags, no grid barrier, no fences).
#define TP 272  // LDS reduce: tile stride (f32)
#define RP 17   // LDS reduce: row pitch (f32)

__global__ __launch_bounds__(512, 2) void krec(
    const _Float16* __restrict__ xgh, const float* __restrict__ ms,
    const _Float16* __restrict__ whh, const _Float16* __restrict__ wr,
    const float* __restrict__ b_hh, const float* __restrict__ b_r,
    const float* __restrict__ h0,
    u64* __restrict__ hmsg, u64* __restrict__ rhmsg,
    float* __restrict__ out) {
  __shared__ float red[48 * TP];      // 8 waves x 6 tiles, padded
  __shared__ _Float16 hsh[512];
  const int tid = threadIdx.x;
  const int lane = tid & 63, w = tid >> 6;
  const int fr = lane & 15, fq = lane >> 4;
  const int g = (int)blockIdx.x >> 5;
  const int slot = (int)blockIdx.x & 31;
  const int colbase = slot * 32;

  // ---- weight fragments -> VGPRs
  half8 wA[6][4], wB[2][4];
  #pragma unroll
  for (int nt = 0; nt < 6; nt++)
    #pragma unroll
    for (int ks = 0; ks < 4; ks++)
      wA[nt][ks] = ld8(whh + (size_t)((nt >> 1) * 1024 + colbase + (nt & 1) * 16 + fr) * 1024
                            + w * 128 + ks * 32 + fq * 8);
  #pragma unroll
  for (int nt = 0; nt < 2; nt++)
    #pragma unroll
    for (int ks = 0; ks < 4; ks++)
      wB[nt][ks] = ld8(wr + (size_t)(colbase + nt * 16 + fr) * 1024
                           + w * 128 + ks * 32 + fq * 8);

  // ---- every thread owns one (row b, col cc) cell
  const int b = tid >> 5, cc = tid & 31;
  const int gc = colbase + cc;
  const int gm = g * 16 + b;
  const float bhr = b_hh[gc], bhz = b_hh[1024 + gc], bhe = b_hh[2048 + gc];
  const float brr = b_r[gc];
  float hreg = h0[(size_t)gm * 1024 + gc];

  // consumer msg addresses: thread (fr,fq,w) reads msgs [fr][w*64+fq*4 + ks*16 + q]
  const u64* hcons = hmsg  + g * 8192 + fr * 512 + w * 64 + fq * 4;
  const u64* rcons = rhmsg + g * 8192 + fr * 512 + w * 64 + fq * 4;
  // producer msg addresses: thread t<256 publishes (row=t>>4, pair p=t&15)
  const int prow = tid >> 4, pp = tid & 15;
  u64* hprod = hmsg  + g * 8192 + prow * 512 + slot * 16 + pp;
  u64* rprod = rhmsg + g * 8192 + prow * 512 + slot * 16 + pp;
  const unsigned* hsrc = (const unsigned*)(hsh + prow * 32 + 2 * pp);

  const f32x4 zero = {0.f, 0.f, 0.f, 0.f};

  // prefetched per-step inputs
  float pxr, pxz, pxe, pxh, ptm;
  {
    const _Float16* xp = xgh + (size_t)gm * 4096;
    pxr = (float)xp[gc]; pxz = (float)xp[1024 + gc];
    pxe = (float)xp[2048 + gc]; pxh = (float)xp[3072 + gc];
    ptm = tanh_(ms[(size_t)gm * 1024 + gc]);
  }

  #pragma clang loop unroll(disable)
  for (int t = 0; t < TSTEPS; t++) {
    // ======== phase A: poll h(t) msgs, gates = sigmoid(xg + h @ Whh^T + b_hh)
    u64 m[16];
    {
      const unsigned tagv = (unsigned)t;
      for (;;) {
        bool ok = true;
        #pragma unroll
        for (int ks = 0; ks < 4; ks++)
          #pragma unroll
          for (int q = 0; q < 4; q++)
            m[ks * 4 + q] = ld_msg(hcons + ks * 16 + q);
        #pragma unroll
        for (int i = 0; i < 16; i++) ok &= ((unsigned)(m[i] >> 32) == tagv);
        if (ok) break;
        __builtin_amdgcn_s_sleep(1);
      }
    }
    half8 av[4];
    #pragma unroll
    for (int ks = 0; ks < 4; ks++) {
      i32x4 u = { (int)(unsigned)m[ks * 4 + 0], (int)(unsigned)m[ks * 4 + 1],
                  (int)(unsigned)m[ks * 4 + 2], (int)(unsigned)m[ks * 4 + 3] };
      av[ks] = __builtin_bit_cast(half8, u);
    }
    f32x4 accA[6];
    #pragma unroll
    for (int nt = 0; nt < 6; nt++) accA[nt] = zero;
    #pragma unroll
    for (int ks = 0; ks < 4; ks++)
      #pragma unroll
      for (int nt = 0; nt < 6; nt++)
        accA[nt] = MFMA(av[ks], wA[nt][ks], accA[nt]);
    #pragma unroll
    for (int nt = 0; nt < 6; nt++)
      #pragma unroll
      for (int r = 0; r < 4; r++)
        red[(w * 6 + nt) * TP + (fq * 4 + r) * RP + fr] = accA[nt][r];
    __syncthreads();                            // S2
    float sr = pxr + bhr, sz = pxz + bhz, se = pxe + bhe;
    {
      const int boff = b * RP + (cc & 15) + (cc >> 4) * TP;
      #pragma unroll
      for (int w8 = 0; w8 < 8; w8++) {
        const float* rp = red + w8 * 6 * TP + boff;
        sr += rp[0]; sz += rp[2 * TP]; se += rp[4 * TP];
      }
    }
    float rg = sigm(sr);
    float zz = sigm(sz), ee = sigm(se);
    hsh[tid] = (_Float16)(rg * hreg);
    __syncthreads();                            // S3
    if (tid < 256)
      st_msg(rprod, ((u64)(unsigned)(t + 1) << 32) | (u64)*hsrc);
    // overlap: prefetch next step's xg/ms while rh msgs propagate
    float nxr = 0.f, nxz = 0.f, nxe = 0.f, nxh = 0.f, ntm = 0.f;
    if (t + 1 < TSTEPS) {
      const _Float16* xp = xgh + (size_t)((t + 1) * 64 + gm) * 4096;
      nxr = (float)xp[gc]; nxz = (float)xp[1024 + gc];
      nxe = (float)xp[2048 + gc]; nxh = (float)xp[3072 + gc];
      ntm = tanh_(ms[(size_t)(t + 1) * 65536 + gm * 1024 + gc]);
    }

    // ======== phase B: poll rh(t) msgs, hhat = tanh(xh + rh @ Wr^T + b_r)
    {
      const unsigned tagv = (unsigned)(t + 1);
      for (;;) {
        bool ok = true;
        #pragma unroll
        for (int ks = 0; ks < 4; ks++)
          #pragma unroll
          for (int q = 0; q < 4; q++)
            m[ks * 4 + q] = ld_msg(rcons + ks * 16 + q);
        #pragma unroll
        for (int i = 0; i < 16; i++) ok &= ((unsigned)(m[i] >> 32) == tagv);
        if (ok) break;
        __builtin_amdgcn_s_sleep(1);
      }
    }
    half8 bv[4];
    #pragma unroll
    for (int ks = 0; ks < 4; ks++) {
      i32x4 u = { (int)(unsigned)m[ks * 4 + 0], (int)(unsigned)m[ks * 4 + 1],
                  (int)(unsigned)m[ks * 4 + 2], (int)(unsigned)m[ks * 4 + 3] };
      bv[ks] = __builtin_bit_cast(half8, u);
    }
    f32x4 accB[2];
    #pragma unroll
    for (int nt = 0; nt < 2; nt++) accB[nt] = zero;
    #pragma unroll
    for (int ks = 0; ks < 4; ks++)
      #pragma unroll
      for (int nt = 0; nt < 2; nt++)
        accB[nt] = MFMA(bv[ks], wB[nt][ks], accB[nt]);
    #pragma unroll
    for (int nt = 0; nt < 2; nt++)
      #pragma unroll
      for (int r = 0; r < 4; r++)
        red[(w * 6 + nt) * TP + (fq * 4 + r) * RP + fr] = accB[nt][r];
    __syncthreads();                            // S6
    float s = pxh + brr;
    {
      const int boff = b * RP + (cc & 15) + (cc >> 4) * TP;
      #pragma unroll
      for (int w8 = 0; w8 < 8; w8++) s += red[w8 * 6 * TP + boff];
    }
    float hh = tanh_(s);
    float hn = zz * hreg + (1.f - zz) * hh + ee * ptm;
    hreg = hn;
    __builtin_nontemporal_store(hn, out + (size_t)t * 65536 + gm * 1024 + gc);
    hsh[tid] = (_Float16)hn;
    __syncthreads();                            // S7
    if (tid < 256)
      st_msg(hprod, ((u64)(unsigned)(t + 1) << 32) | (u64)*hsrc);
    pxr = nxr; pxz = nxz; pxe = nxe; pxh = nxh; ptm = ntm;
  }
  out[(size_t)TSTEPS * 65536 + gm * 1024 + gc] = hreg;
}

extern "C" void kernel_launch(void* const* d_in, const int* in_sizes, int n_in,
                              void* d_out, int out_size, void* d_ws, size_t ws_size,
                              hipStream_t stream) {
  const float* xs   = (const float*)d_in[0];
  const float* ms   = (const float*)d_in[1];
  const float* h0   = (const float*)d_in[2];
  const float* W_ih = (const float*)d_in[3];
  const float* b_ih = (const float*)d_in[4];
  const float* W_hh = (const float*)d_in[5];
  const float* b_hh = (const float*)d_in[6];
  const float* W_xh = (const float*)d_in[7];
  const float* b_xh = (const float*)d_in[8];
  const float* W_r  = (const float*)d_in[9];
  const float* b_r  = (const float*)d_in[10];

  char* ws = (char*)d_ws;
  size_t off = 0;
  _Float16* xs_h = (_Float16*)(ws + off); off += 67108864;   // [32768][1024] f16
  _Float16* wcat = (_Float16*)(ws + off); off += 8388608;    // [4096][1024] f16
  _Float16* whh  = (_Float16*)(ws + off); off += 6291456;    // [3072][1024] f16
  _Float16* wr   = (_Float16*)(ws + off); off += 2097152;    // [1024][1024] f16
  _Float16* xgh  = (_Float16*)(ws + off); off += 268435456;  // [32768][4096] f16
  u64* hmsg  = (u64*)(ws + off); off += 262144;              // 4 grp x 8192 msgs
  u64* rhmsg = (u64*)(ws + off); off += 262144;              // 4 grp x 8192 msgs

  kconv<<<2048, 256, 0, stream>>>(xs, W_ih, W_xh, W_hh, W_r, h0,
                                  xs_h, wcat, whh, wr, hmsg, rhmsg);
  kgemm<<<dim3(32, 256), 256, 0, stream>>>(xs_h, wcat, b_ih, b_xh, xgh);
  krec<<<128, 512, 0, stream>>>(xgh, ms, whh, wr, b_hh, b_r, h0,
                                hmsg, rhmsg, (float*)d_out);
}

// Round 7
// 5845.298 us; speedup vs baseline: 1.0317x; 1.0317x over previous
//
#include <hip/hip_runtime.h>
#include <stdint.h>

#define TSTEPS 512

typedef __attribute__((ext_vector_type(8))) _Float16 half8;
typedef __attribute__((ext_vector_type(4))) _Float16 half4;
typedef __attribute__((ext_vector_type(2))) _Float16 half2v;
typedef __attribute__((ext_vector_type(4))) float f32x4;
typedef __attribute__((ext_vector_type(4))) float float4v;
typedef __attribute__((ext_vector_type(4))) int i32x4;
typedef unsigned long long u64;

static __device__ __forceinline__ float sigm(float x) { return 1.f / (1.f + __expf(-x)); }
static __device__ __forceinline__ float tanh_(float x) {
  x = fminf(15.f, fmaxf(-15.f, x));
  float e = __expf(-2.f * x);
  return (1.f - e) / (1.f + e);
}
static __device__ __forceinline__ half8 ld8(const _Float16* p) { return *(const half8*)p; }
static __device__ __forceinline__ f32x4 MFMA(half8 a, half8 b, f32x4 c) {
  return __builtin_amdgcn_mfma_f32_16x16x32_f16(a, b, c, 0, 0, 0);
}

// ---- self-validating messages through the MALL (relaxed agent atomics).
// msg u64 = { lo32: half2 data, hi32: step tag }. u64 single-copy atomicity
// means tag==t => data is step t's. Tags are the correctness truth; the hint
// line is only a cheap gate to avoid r6's bulk-poll MALL congestion.
static __device__ __forceinline__ u64 ld_msg(const u64* p) {
  return __hip_atomic_load(p, __ATOMIC_RELAXED, __HIP_MEMORY_SCOPE_AGENT);
}
static __device__ __forceinline__ void st_msg(u64* p, u64 v) {
  __hip_atomic_store(p, v, __ATOMIC_RELAXED, __HIP_MEMORY_SCOPE_AGENT);
}
static __device__ __forceinline__ void wait_hint(const unsigned* line, unsigned tag, int tid) {
  const unsigned* p = line + (tid & 31);
  while (!__all(__hip_atomic_load(p, __ATOMIC_RELAXED, __HIP_MEMORY_SCOPE_AGENT) >= tag))
    __builtin_amdgcn_s_sleep(1);
}
// bulk-load 16 msgs once; verify tags; rare retry (hint raced ahead of data)
static __device__ __forceinline__ void load_frag(const u64* base, unsigned tagv, half8* out4) {
  u64 m[16];
  for (;;) {
    bool ok = true;
    #pragma unroll
    for (int ks = 0; ks < 4; ks++)
      #pragma unroll
      for (int q = 0; q < 4; q++)
        m[ks * 4 + q] = ld_msg(base + ks * 16 + q);
    #pragma unroll
    for (int i = 0; i < 16; i++) ok &= ((unsigned)(m[i] >> 32) == tagv);
    if (ok) break;
    __builtin_amdgcn_s_sleep(1);
  }
  #pragma unroll
  for (int ks = 0; ks < 4; ks++) {
    i32x4 u = { (int)(unsigned)m[ks * 4 + 0], (int)(unsigned)m[ks * 4 + 1],
                (int)(unsigned)m[ks * 4 + 2], (int)(unsigned)m[ks * 4 + 3] };
    out4[ks] = __builtin_bit_cast(half8, u);
  }
}

// ---------------- f32 -> f16 conversion / msg-buffer init ----------------
__global__ __launch_bounds__(256) void kconv(
    const float* __restrict__ xs, const float* __restrict__ wih,
    const float* __restrict__ wxh, const float* __restrict__ whhf,
    const float* __restrict__ wrf, const float* __restrict__ h0,
    _Float16* __restrict__ xs_h, _Float16* __restrict__ wcat,
    _Float16* __restrict__ whh, _Float16* __restrict__ wr,
    u64* __restrict__ hmsg, u64* __restrict__ rhmsg) {
  const long n1 = 8388608;   // xs / 4
  const long n2 = 1048576;   // wcat / 4
  const long n3 = 786432;    // whh / 4
  const long n4 = 262144;    // wr / 4
  const long b4 = n1 + n2 + n3 + n4;
  const long n5 = 32768;     // hmsg u64 count (4 grp x 16 row x 512 pair)
  const long n6 = 32768;     // rhmsg u64 count
  const long total = b4 + n5 + n6;
  for (long i = (long)blockIdx.x * 256 + threadIdx.x; i < total; i += (long)gridDim.x * 256) {
    if (i < b4) {
      const float* s; _Float16* d;
      if (i < n1) { s = xs + i * 4; d = xs_h + i * 4; }
      else if (i < n1 + n2) {
        long e = (i - n1) * 4;
        s = (e < 3145728) ? (wih + e) : (wxh + (e - 3145728));
        d = wcat + e;
      } else if (i < n1 + n2 + n3) { long e = (i - n1 - n2) * 4; s = whhf + e; d = whh + e; }
      else { long e = (i - n1 - n2 - n3) * 4; s = wrf + e; d = wr + e; }
      float4v v = *(const float4v*)s;
      half4 o = { (_Float16)v.x, (_Float16)v.y, (_Float16)v.z, (_Float16)v.w };
      *(half4*)d = o;
    } else if (i < b4 + n5) {
      // hmsg: h0 data, tag 0  (replay-safe full reset)
      long e = i - b4;
      int g = (int)(e >> 13), rem = (int)(e & 8191);
      int row = rem >> 9, pr = rem & 511;
      const float* hp = h0 + (size_t)(g * 16 + row) * 1024 + 2 * pr;
      half2v h2 = { (_Float16)hp[0], (_Float16)hp[1] };
      hmsg[e] = (u64)(unsigned)__builtin_bit_cast(unsigned, h2);
    } else {
      // rhmsg: sentinel tag (never matches any expected tag 1..512)
      rhmsg[i - b4 - n5] = 0xFFFFFFFF00000000ull;
    }
  }
}

// ---------------- big input-side GEMM: xgh[32768][4096] = xs @ [W_ih;W_xh]^T + bias ----------------
__global__ __launch_bounds__(256) void kgemm(
    const _Float16* __restrict__ X, const _Float16* __restrict__ W,
    const float* __restrict__ b_ih, const float* __restrict__ b_xh,
    _Float16* __restrict__ C) {
  __shared__ _Float16 As[128 * 40], Bs[128 * 40];
  const int tid = threadIdx.x;
  const int lane = tid & 63;
  const int w = tid >> 6;
  const int wm = (w >> 1) * 64, wn = (w & 1) * 64;
  const int bn = blockIdx.x * 128;
  const int bm = blockIdx.y * 128;
  const int arow = tid >> 2;
  const int kk8 = (tid & 3) * 8;
  const int fr = lane & 15, fq = lane >> 4;
  const f32x4 zero = {0.f, 0.f, 0.f, 0.f};
  f32x4 acc[4][4];
  #pragma unroll
  for (int a = 0; a < 4; a++)
    #pragma unroll
    for (int b = 0; b < 4; b++) acc[a][b] = zero;
  for (int kt = 0; kt < 1024; kt += 32) {
    __syncthreads();
    #pragma unroll
    for (int j = 0; j < 2; j++) {
      int r = j * 64 + arow;
      *(half8*)(As + r * 40 + kk8) = ld8(X + (size_t)(bm + r) * 1024 + kt + kk8);
      *(half8*)(Bs + r * 40 + kk8) = ld8(W + (size_t)(bn + r) * 1024 + kt + kk8);
    }
    __syncthreads();
    half8 af[4], bfr[4];
    #pragma unroll
    for (int i = 0; i < 4; i++) {
      af[i]  = *(const half8*)(As + (wm + i * 16 + fr) * 40 + fq * 8);
      bfr[i] = *(const half8*)(Bs + (wn + i * 16 + fr) * 40 + fq * 8);
    }
    #pragma unroll
    for (int mi = 0; mi < 4; mi++)
      #pragma unroll
      for (int ni = 0; ni < 4; ni++)
        acc[mi][ni] = MFMA(af[mi], bfr[ni], acc[mi][ni]);
  }
  #pragma unroll
  for (int mi = 0; mi < 4; mi++)
    #pragma unroll
    for (int ni = 0; ni < 4; ni++) {
      int col = bn + wn + ni * 16 + fr;
      float bias = (col < 3072) ? b_ih[col] : b_xh[col - 3072];
      #pragma unroll
      for (int r = 0; r < 4; r++) {
        int row = bm + wm + mi * 16 + fq * 4 + r;
        C[(size_t)row * 4096 + col] = (_Float16)(acc[mi][ni][r] + bias);
      }
    }
}

// ---------------- persistent recurrent kernel ----------------
// 4 groups x 32 wgs x 512 thr. Group owns 16 batch rows; wg owns 32 h-cols.
// Wave w holds K-slice [128w,128w+128) of W_hh/W_r; split-K reduced in LDS.
// Exchange: tagged u64 msgs (truth) + per-wg hint dwords (cheap poll gate).
// No producer acks, no fences, no grid barrier.
#define TP 272  // LDS reduce: tile stride (f32)
#define RP 17   // LDS reduce: row pitch (f32)

__global__ __launch_bounds__(512, 2) void krec(
    const _Float16* __restrict__ xgh, const float* __restrict__ ms,
    const _Float16* __restrict__ whh, const _Float16* __restrict__ wr,
    const float* __restrict__ b_hh, const float* __restrict__ b_r,
    const float* __restrict__ h0,
    u64* __restrict__ hmsg, u64* __restrict__ rhmsg,
    float* __restrict__ out, unsigned* __restrict__ ctr) {
  __shared__ float red[48 * TP];      // 8 waves x 6 tiles, padded
  const int tid = threadIdx.x;
  const int lane = tid & 63, w = tid >> 6;
  const int fr = lane & 15, fq = lane >> 4;
  const int g = (int)blockIdx.x >> 5;
  const int slot = (int)blockIdx.x & 31;
  const int colbase = slot * 32;
  unsigned* hintA = ctr + (g * 2 + 0) * 32;   // rh(t) published (tag t+1)
  unsigned* hintB = ctr + (g * 2 + 1) * 32;   // h(t) published (tag t)

  // ---- weight fragments -> VGPRs
  half8 wA[6][4], wB[2][4];
  #pragma unroll
  for (int nt = 0; nt < 6; nt++)
    #pragma unroll
    for (int ks = 0; ks < 4; ks++)
      wA[nt][ks] = ld8(whh + (size_t)((nt >> 1) * 1024 + colbase + (nt & 1) * 16 + fr) * 1024
                            + w * 128 + ks * 32 + fq * 8);
  #pragma unroll
  for (int nt = 0; nt < 2; nt++)
    #pragma unroll
    for (int ks = 0; ks < 4; ks++)
      wB[nt][ks] = ld8(wr + (size_t)(colbase + nt * 16 + fr) * 1024
                           + w * 128 + ks * 32 + fq * 8);

  // ---- every thread owns one (row b, col cc) cell
  const int b = tid >> 5, cc = tid & 31;
  const int gc = colbase + cc;
  const int gm = g * 16 + b;
  const float bhr = b_hh[gc], bhz = b_hh[1024 + gc], bhe = b_hh[2048 + gc];
  const float brr = b_r[gc];
  float hreg = h0[(size_t)gm * 1024 + gc];

  // consumer msg addresses: thread (fr,fq,w) reads pairs [fr][w*64+fq*4 +16ks+q]
  const u64* hcons = hmsg  + g * 8192 + fr * 512 + w * 64 + fq * 4;
  const u64* rcons = rhmsg + g * 8192 + fr * 512 + w * 64 + fq * 4;
  // producer (even-cc threads): row b, global pair slot*16 + (cc>>1)
  u64* hprod = hmsg  + g * 8192 + b * 512 + slot * 16 + (cc >> 1);
  u64* rprod = rhmsg + g * 8192 + b * 512 + slot * 16 + (cc >> 1);

  const f32x4 zero = {0.f, 0.f, 0.f, 0.f};

  // prefetched per-step inputs
  float pxr, pxz, pxe, pxh, ptm;
  {
    const _Float16* xp = xgh + (size_t)gm * 4096;
    pxr = (float)xp[gc]; pxz = (float)xp[1024 + gc];
    pxe = (float)xp[2048 + gc]; pxh = (float)xp[3072 + gc];
    ptm = tanh_(ms[(size_t)gm * 1024 + gc]);
  }

  #pragma clang loop unroll(disable)
  for (int t = 0; t < TSTEPS; t++) {
    // ======== phase A: h(t) -> gates; publish rh (tag t+1)
    wait_hint(hintB, (unsigned)t, tid);
    half8 av[4];
    load_frag(hcons, (unsigned)t, av);
    f32x4 accA[6];
    #pragma unroll
    for (int nt = 0; nt < 6; nt++) accA[nt] = zero;
    #pragma unroll
    for (int ks = 0; ks < 4; ks++)
      #pragma unroll
      for (int nt = 0; nt < 6; nt++)
        accA[nt] = MFMA(av[ks], wA[nt][ks], accA[nt]);
    #pragma unroll
    for (int nt = 0; nt < 6; nt++)
      #pragma unroll
      for (int r = 0; r < 4; r++)
        red[(w * 6 + nt) * TP + (fq * 4 + r) * RP + fr] = accA[nt][r];
    __syncthreads();                            // S1: reduce ready
    float sr = pxr + bhr, sz = pxz + bhz, se = pxe + bhe;
    {
      const int boff = b * RP + (cc & 15) + (cc >> 4) * TP;
      #pragma unroll
      for (int w8 = 0; w8 < 8; w8++) {
        const float* rp = red + w8 * 6 * TP + boff;
        sr += rp[0]; sz += rp[2 * TP]; se += rp[4 * TP];
      }
    }
    float rg = sigm(sr);
    float zz = sigm(sz), ee = sigm(se);
    // publish rh from registers: pair lane cc with cc+1 via shfl
    {
      float rv = rg * hreg;
      unsigned lo = (unsigned)__builtin_bit_cast(unsigned short, (_Float16)rv);
      unsigned hi = (unsigned)__shfl_down((int)lo, 1);
      if (!(cc & 1))
        st_msg(rprod, ((u64)(unsigned)(t + 1) << 32) | (u64)((hi << 16) | lo));
    }
    __syncthreads();                            // S2: all publishes issued + red[] safe
    if (tid == 0)
      __hip_atomic_store(hintA + slot, (unsigned)(t + 1),
                         __ATOMIC_RELAXED, __HIP_MEMORY_SCOPE_AGENT);
    // overlap: prefetch next step's xg/ms while rh msgs propagate
    float nxr = 0.f, nxz = 0.f, nxe = 0.f, nxh = 0.f, ntm = 0.f;
    if (t + 1 < TSTEPS) {
      const _Float16* xp = xgh + (size_t)((t + 1) * 64 + gm) * 4096;
      nxr = (float)xp[gc]; nxz = (float)xp[1024 + gc];
      nxe = (float)xp[2048 + gc]; nxh = (float)xp[3072 + gc];
      ntm = tanh_(ms[(size_t)(t + 1) * 65536 + gm * 1024 + gc]);
    }

    // ======== phase B: rh(t) -> hhat; h update; publish h (tag t+1)
    wait_hint(hintA, (unsigned)(t + 1), tid);
    half8 bv[4];
    load_frag(rcons, (unsigned)(t + 1), bv);
    f32x4 accB[2];
    #pragma unroll
    for (int nt = 0; nt < 2; nt++) accB[nt] = zero;
    #pragma unroll
    for (int ks = 0; ks < 4; ks++)
      #pragma unroll
      for (int nt = 0; nt < 2; nt++)
        accB[nt] = MFMA(bv[ks], wB[nt][ks], accB[nt]);
    #pragma unroll
    for (int nt = 0; nt < 2; nt++)
      #pragma unroll
      for (int r = 0; r < 4; r++)
        red[(w * 6 + nt) * TP + (fq * 4 + r) * RP + fr] = accB[nt][r];
    __syncthreads();                            // S3: reduce ready
    float s = pxh + brr;
    {
      const int boff = b * RP + (cc & 15) + (cc >> 4) * TP;
      #pragma unroll
      for (int w8 = 0; w8 < 8; w8++) s += red[w8 * 6 * TP + boff];
    }
    float hh = tanh_(s);
    float hn = zz * hreg + (1.f - zz) * hh + ee * ptm;
    hreg = hn;
    __builtin_nontemporal_store(hn, out + (size_t)t * 65536 + gm * 1024 + gc);
    {
      unsigned lo = (unsigned)__builtin_bit_cast(unsigned short, (_Float16)hn);
      unsigned hi = (unsigned)__shfl_down((int)lo, 1);
      if (!(cc & 1))
        st_msg(hprod, ((u64)(unsigned)(t + 1) << 32) | (u64)((hi << 16) | lo));
    }
    __syncthreads();                            // S4: all publishes issued + red[] safe
    if (tid == 0)
      __hip_atomic_store(hintB + slot, (unsigned)(t + 1),
                         __ATOMIC_RELAXED, __HIP_MEMORY_SCOPE_AGENT);
    pxr = nxr; pxz = nxz; pxe = nxe; pxh = nxh; ptm = ntm;
  }
  out[(size_t)TSTEPS * 65536 + gm * 1024 + gc] = hreg;
}

extern "C" void kernel_launch(void* const* d_in, const int* in_sizes, int n_in,
                              void* d_out, int out_size, void* d_ws, size_t ws_size,
                              hipStream_t stream) {
  const float* xs   = (const float*)d_in[0];
  const float* ms   = (const float*)d_in[1];
  const float* h0   = (const float*)d_in[2];
  const float* W_ih = (const float*)d_in[3];
  const float* b_ih = (const float*)d_in[4];
  const float* W_hh = (const float*)d_in[5];
  const float* b_hh = (const float*)d_in[6];
  const float* W_xh = (const float*)d_in[7];
  const float* b_xh = (const float*)d_in[8];
  const float* W_r  = (const float*)d_in[9];
  const float* b_r  = (const float*)d_in[10];

  char* ws = (char*)d_ws;
  size_t off = 0;
  _Float16* xs_h = (_Float16*)(ws + off); off += 67108864;   // [32768][1024] f16
  _Float16* wcat = (_Float16*)(ws + off); off += 8388608;    // [4096][1024] f16
  _Float16* whh  = (_Float16*)(ws + off); off += 6291456;    // [3072][1024] f16
  _Float16* wr   = (_Float16*)(ws + off); off += 2097152;    // [1024][1024] f16
  _Float16* xgh  = (_Float16*)(ws + off); off += 268435456;  // [32768][4096] f16
  u64* hmsg  = (u64*)(ws + off); off += 262144;              // 4 grp x 8192 msgs
  u64* rhmsg = (u64*)(ws + off); off += 262144;              // 4 grp x 8192 msgs
  unsigned* ctr = (unsigned*)(ws + off); off += 1024;        // hint lines

  hipMemsetAsync(ctr, 0, 1024, stream);
  kconv<<<2048, 256, 0, stream>>>(xs, W_ih, W_xh, W_hh, W_r, h0,
                                  xs_h, wcat, whh, wr, hmsg, rhmsg);
  kgemm<<<dim3(32, 256), 256, 0, stream>>>(xs_h, wcat, b_ih, b_xh, xgh);
  krec<<<128, 512, 0, stream>>>(xgh, ms, whh, wr, b_hh, b_r, h0,
                                hmsg, rhmsg, (float*)d_out, ctr);
}

// Round 8
// 4455.490 us; speedup vs baseline: 1.3535x; 1.3119x over previous
//
#include <hip/hip_runtime.h>
#include <stdint.h>

#define TSTEPS 512

typedef __attribute__((ext_vector_type(8))) _Float16 half8;
typedef __attribute__((ext_vector_type(4))) _Float16 half4;
typedef __attribute__((ext_vector_type(4))) float f32x4;
typedef __attribute__((ext_vector_type(4))) float float4v;
typedef __attribute__((ext_vector_type(4))) int i32x4;
typedef unsigned long long u64;

static __device__ __forceinline__ float sigm(float x) { return 1.f / (1.f + __expf(-x)); }
static __device__ __forceinline__ float tanh_(float x) {
  x = fminf(15.f, fmaxf(-15.f, x));
  float e = __expf(-2.f * x);
  return (1.f - e) / (1.f + e);
}
static __device__ __forceinline__ half8 ld8(const _Float16* p) { return *(const half8*)p; }
static __device__ __forceinline__ f32x4 MFMA(half8 a, half8 b, f32x4 c) {
  return __builtin_amdgcn_mfma_f32_16x16x32_f16(a, b, c, 0, 0, 0);
}
// pin a 128-bit value into VGPRs: "+v" makes the register copy authoritative,
// so the compiler can never re-sink the originating load into the loop.
static __device__ __forceinline__ void pin8(half8& v) {
  i32x4 t = __builtin_bit_cast(i32x4, v);
  asm volatile("" : "+v"(t));
  v = __builtin_bit_cast(half8, t);
}

// ---- cross-XCD msgs: agent-scope RELAXED atomics (MALL-homed, r4/r5-proven).
// Ordering: msg stores -> vmcnt(0) -> __syncthreads -> flag store;
// consumer: flag poll -> msg loads.
struct U64x2 { u64 x, y; };
static __device__ __forceinline__ half8 ld_msg16(const u64* p) {
  u64 a = __hip_atomic_load(p,     __ATOMIC_RELAXED, __HIP_MEMORY_SCOPE_AGENT);
  u64 b = __hip_atomic_load(p + 1, __ATOMIC_RELAXED, __HIP_MEMORY_SCOPE_AGENT);
  U64x2 u{a, b};
  return __builtin_bit_cast(half8, u);
}
static __device__ __forceinline__ void st_msg(u64* p, u64 v) {
  __hip_atomic_store(p, v, __ATOMIC_RELAXED, __HIP_MEMORY_SCOPE_AGENT);
}
static __device__ __forceinline__ void wait_flags(const unsigned* line, unsigned tag) {
  const unsigned* p = line + (threadIdx.x & 31);
  while (!__all(__hip_atomic_load(p, __ATOMIC_RELAXED, __HIP_MEMORY_SCOPE_AGENT) >= tag))
    __builtin_amdgcn_s_sleep(1);
  asm volatile("" ::: "memory");   // keep msg loads after the poll
}

// ---------------- f32 -> f16 conversion / init ----------------
__global__ __launch_bounds__(256) void kconv(
    const float* __restrict__ xs, const float* __restrict__ wih,
    const float* __restrict__ wxh, const float* __restrict__ whhf,
    const float* __restrict__ wrf, const float* __restrict__ h0,
    _Float16* __restrict__ xs_h, _Float16* __restrict__ wcat,
    _Float16* __restrict__ whh, _Float16* __restrict__ wr,
    _Float16* __restrict__ hx) {
  const long n1 = 8388608;   // xs / 4
  const long n2 = 1048576;   // wcat / 4
  const long n3 = 786432;    // whh / 4
  const long n4 = 262144;    // wr / 4
  const long n5 = 16384;     // h0 / 4 -> hx parity-0
  const long total = n1 + n2 + n3 + n4 + n5;
  for (long i = (long)blockIdx.x * 256 + threadIdx.x; i < total; i += (long)gridDim.x * 256) {
    const float* s; _Float16* d;
    if (i < n1) { s = xs + i * 4; d = xs_h + i * 4; }
    else if (i < n1 + n2) {
      long e = (i - n1) * 4;
      s = (e < 3145728) ? (wih + e) : (wxh + (e - 3145728));
      d = wcat + e;
    } else if (i < n1 + n2 + n3) { long e = (i - n1 - n2) * 4; s = whhf + e; d = whh + e; }
    else if (i < n1 + n2 + n3 + n4) { long e = (i - n1 - n2 - n3) * 4; s = wrf + e; d = wr + e; }
    else { long e = (i - n1 - n2 - n3 - n4) * 4; s = h0 + e; d = hx + e; }
    float4v v = *(const float4v*)s;
    half4 o = { (_Float16)v.x, (_Float16)v.y, (_Float16)v.z, (_Float16)v.w };
    *(half4*)d = o;
  }
}

// ---------------- big input-side GEMM: xgh[32768][4096] = xs @ [W_ih;W_xh]^T + bias ----------------
__global__ __launch_bounds__(256) void kgemm(
    const _Float16* __restrict__ X, const _Float16* __restrict__ W,
    const float* __restrict__ b_ih, const float* __restrict__ b_xh,
    _Float16* __restrict__ C) {
  __shared__ _Float16 As[128 * 40], Bs[128 * 40];
  const int tid = threadIdx.x;
  const int lane = tid & 63;
  const int w = tid >> 6;
  const int wm = (w >> 1) * 64, wn = (w & 1) * 64;
  const int bn = blockIdx.x * 128;
  const int bm = blockIdx.y * 128;
  const int arow = tid >> 2;
  const int kk8 = (tid & 3) * 8;
  const int fr = lane & 15, fq = lane >> 4;
  const f32x4 zero = {0.f, 0.f, 0.f, 0.f};
  f32x4 acc[4][4];
  #pragma unroll
  for (int a = 0; a < 4; a++)
    #pragma unroll
    for (int b = 0; b < 4; b++) acc[a][b] = zero;
  for (int kt = 0; kt < 1024; kt += 32) {
    __syncthreads();
    #pragma unroll
    for (int j = 0; j < 2; j++) {
      int r = j * 64 + arow;
      *(half8*)(As + r * 40 + kk8) = ld8(X + (size_t)(bm + r) * 1024 + kt + kk8);
      *(half8*)(Bs + r * 40 + kk8) = ld8(W + (size_t)(bn + r) * 1024 + kt + kk8);
    }
    __syncthreads();
    half8 af[4], bfr[4];
    #pragma unroll
    for (int i = 0; i < 4; i++) {
      af[i]  = *(const half8*)(As + (wm + i * 16 + fr) * 40 + fq * 8);
      bfr[i] = *(const half8*)(Bs + (wn + i * 16 + fr) * 40 + fq * 8);
    }
    #pragma unroll
    for (int mi = 0; mi < 4; mi++)
      #pragma unroll
      for (int ni = 0; ni < 4; ni++)
        acc[mi][ni] = MFMA(af[mi], bfr[ni], acc[mi][ni]);
  }
  #pragma unroll
  for (int mi = 0; mi < 4; mi++)
    #pragma unroll
    for (int ni = 0; ni < 4; ni++) {
      int col = bn + wn + ni * 16 + fr;
      float bias = (col < 3072) ? b_ih[col] : b_xh[col - 3072];
      #pragma unroll
      for (int r = 0; r < 4; r++) {
        int row = bm + wm + mi * 16 + fq * 4 + r;
        C[(size_t)row * 4096 + col] = (_Float16)(acc[mi][ni][r] + bias);
      }
    }
}

// ---------------- persistent recurrent kernel ----------------
// 4 groups x 32 wgs x 512 thr. Group owns 16 batch rows; wg owns 32 h-cols;
// full K=1024 of its W_hh/W_r rows PINNED in VGPRs. Wave w = K-slice
// [128w,128w+128); split-K reduced in LDS. h/rh exchanged as u64 MALL msgs,
// parity double-buffered; per-wg flag dwords (r5 protocol, no RMW).
#define RP 20            // LDS reduce row pitch (f32)
#define TP (16 * RP)     // LDS reduce tile stride

__global__ __launch_bounds__(512, 2) void krec(
    const _Float16* __restrict__ xgh, const float* __restrict__ ms,
    const _Float16* __restrict__ whh, const _Float16* __restrict__ wr,
    const float* __restrict__ b_hh, const float* __restrict__ b_r,
    const float* __restrict__ h0,
    u64* __restrict__ hmsg, u64* __restrict__ rhmsg,
    float* __restrict__ out, unsigned* __restrict__ ctr) {
  __shared__ float red[48 * TP];      // 8 waves x 6 tiles, pitch-padded (60KB)
  const int tid = threadIdx.x;
  const int lane = tid & 63, w = tid >> 6;
  const int fr = lane & 15, fq = lane >> 4;
  const int g = (int)blockIdx.x >> 5;
  const int slot = (int)blockIdx.x & 31;
  const int colbase = slot * 32;
  unsigned* flagA = ctr + (g * 2 + 0) * 32;   // rh(t) published => t+1
  unsigned* flagB = ctr + (g * 2 + 1) * 32;   // h(t) published  => t

  // ---- weight fragments -> VGPRs, PINNED for all 512 steps
  half8 wA[6][4], wB[2][4];
  #pragma unroll
  for (int nt = 0; nt < 6; nt++)
    #pragma unroll
    for (int ks = 0; ks < 4; ks++)
      wA[nt][ks] = ld8(whh + (size_t)((nt >> 1) * 1024 + colbase + (nt & 1) * 16 + fr) * 1024
                            + w * 128 + ks * 32 + fq * 8);
  #pragma unroll
  for (int nt = 0; nt < 2; nt++)
    #pragma unroll
    for (int ks = 0; ks < 4; ks++)
      wB[nt][ks] = ld8(wr + (size_t)(colbase + nt * 16 + fr) * 1024
                           + w * 128 + ks * 32 + fq * 8);
  #pragma unroll
  for (int nt = 0; nt < 6; nt++)
    #pragma unroll
    for (int ks = 0; ks < 4; ks++) pin8(wA[nt][ks]);
  #pragma unroll
  for (int nt = 0; nt < 2; nt++)
    #pragma unroll
    for (int ks = 0; ks < 4; ks++) pin8(wB[nt][ks]);

  // ---- every thread owns one (row b, col cc) cell
  const int b = tid >> 5, cc = tid & 31;
  const int gc = colbase + cc;
  const int gm = g * 16 + b;
  const float bhr = b_hh[gc], bhz = b_hh[1024 + gc], bhe = b_hh[2048 + gc];
  const float brr = b_r[gc];
  float hreg = h0[(size_t)gm * 1024 + gc];

  // msg addresses (parity block = 16384 u64)
  const u64* hcons = hmsg  + (g * 16 + fr) * 256 + w * 32 + fq * 2;
  const u64* rcons = rhmsg + (g * 16 + fr) * 256 + w * 32 + fq * 2;
  u64* hprod = hmsg  + gm * 256 + (gc >> 2);
  u64* rprod = rhmsg + gm * 256 + (gc >> 2);

  const f32x4 zero = {0.f, 0.f, 0.f, 0.f};

  // prefetched per-step inputs
  float pxr, pxz, pxe, pxh, ptm;
  {
    const _Float16* xp = xgh + (size_t)gm * 4096;
    pxr = (float)xp[gc]; pxz = (float)xp[1024 + gc];
    pxe = (float)xp[2048 + gc]; pxh = (float)xp[3072 + gc];
    ptm = tanh_(ms[(size_t)gm * 1024 + gc]);
  }

  #pragma clang loop unroll(disable)
  for (int t = 0; t < TSTEPS; t++) {
    const int ph = t & 1;
    // ======== phase A: h(t) -> gates; publish rh(t)
    wait_flags(flagB, (unsigned)t);
    half8 av[4];
    #pragma unroll
    for (int ks = 0; ks < 4; ks++)
      av[ks] = ld_msg16(hcons + ph * 16384 + ks * 8);
    f32x4 accA[6];
    #pragma unroll
    for (int nt = 0; nt < 6; nt++) accA[nt] = zero;
    #pragma unroll
    for (int ks = 0; ks < 4; ks++)
      #pragma unroll
      for (int nt = 0; nt < 6; nt++)
        accA[nt] = MFMA(av[ks], wA[nt][ks], accA[nt]);
    #pragma unroll
    for (int nt = 0; nt < 6; nt++)
      #pragma unroll
      for (int r = 0; r < 4; r++)
        red[(w * 6 + nt) * TP + (fq * 4 + r) * RP + fr] = accA[nt][r];
    __syncthreads();                            // S1: reduce ready
    float sr = pxr + bhr, sz = pxz + bhz, se = pxe + bhe;
    {
      const int boff = b * RP + (cc & 15) + (cc >> 4) * TP;
      #pragma unroll
      for (int w8 = 0; w8 < 8; w8++) {
        const float* rp = red + w8 * 6 * TP + boff;
        sr += rp[0]; sz += rp[2 * TP]; se += rp[4 * TP];
      }
    }
    float rg = sigm(sr);
    float zz = sigm(sz), ee = sigm(se);
    // publish rh straight from registers (4 cols -> one u64)
    {
      float rv = rg * hreg;
      unsigned us = (unsigned)(unsigned short)__builtin_bit_cast(unsigned short, (_Float16)rv);
      unsigned v01 = us | (((unsigned)__shfl_down((int)us, 1) & 0xFFFFu) << 16);
      unsigned v23 = (unsigned)__shfl_down((int)v01, 2);
      if (!(cc & 3))
        st_msg(rprod + ph * 16384, ((u64)v23 << 32) | (u64)v01);
    }
    asm volatile("s_waitcnt vmcnt(0)" ::: "memory");
    __syncthreads();                            // S2: all rh msgs acked (+red guard)
    if (tid == 0)
      __hip_atomic_store(flagA + slot, (unsigned)(t + 1),
                         __ATOMIC_RELAXED, __HIP_MEMORY_SCOPE_AGENT);
    // overlap: prefetch next step's xg/ms while rh msgs propagate
    float nxr = 0.f, nxz = 0.f, nxe = 0.f, nxh = 0.f, ntm = 0.f;
    if (t + 1 < TSTEPS) {
      const _Float16* xp = xgh + (size_t)((t + 1) * 64 + gm) * 4096;
      nxr = (float)xp[gc]; nxz = (float)xp[1024 + gc];
      nxe = (float)xp[2048 + gc]; nxh = (float)xp[3072 + gc];
      ntm = tanh_(ms[(size_t)(t + 1) * 65536 + gm * 1024 + gc]);
    }

    // ======== phase B: rh(t) -> hhat; h update; publish h(t+1)
    wait_flags(flagA, (unsigned)(t + 1));
    half8 bv[4];
    #pragma unroll
    for (int ks = 0; ks < 4; ks++)
      bv[ks] = ld_msg16(rcons + ph * 16384 + ks * 8);
    f32x4 accB[2];
    #pragma unroll
    for (int nt = 0; nt < 2; nt++) accB[nt] = zero;
    #pragma unroll
    for (int ks = 0; ks < 4; ks++)
      #pragma unroll
      for (int nt = 0; nt < 2; nt++)
        accB[nt] = MFMA(bv[ks], wB[nt][ks], accB[nt]);
    #pragma unroll
    for (int nt = 0; nt < 2; nt++)
      #pragma unroll
      for (int r = 0; r < 4; r++)
        red[(w * 6 + nt) * TP + (fq * 4 + r) * RP + fr] = accB[nt][r];
    __syncthreads();                            // S3: reduce ready
    float s = pxh + brr;
    {
      const int boff = b * RP + (cc & 15) + (cc >> 4) * TP;
      #pragma unroll
      for (int w8 = 0; w8 < 8; w8++) s += red[w8 * 6 * TP + boff];
    }
    float hh = tanh_(s);
    float hn = zz * hreg + (1.f - zz) * hh + ee * ptm;
    hreg = hn;
    {
      unsigned us = (unsigned)(unsigned short)__builtin_bit_cast(unsigned short, (_Float16)hn);
      unsigned v01 = us | (((unsigned)__shfl_down((int)us, 1) & 0xFFFFu) << 16);
      unsigned v23 = (unsigned)__shfl_down((int)v01, 2);
      if (!(cc & 3))
        st_msg(hprod + (ph ^ 1) * 16384, ((u64)v23 << 32) | (u64)v01);
    }
    asm volatile("s_waitcnt vmcnt(0)" ::: "memory");
    __syncthreads();                            // S4: all h msgs acked (+red guard)
    if (tid == 0)
      __hip_atomic_store(flagB + slot, (unsigned)(t + 1),
                         __ATOMIC_RELAXED, __HIP_MEMORY_SCOPE_AGENT);
    // out store AFTER flag: its HBM ack drains off the critical path
    __builtin_nontemporal_store(hn, out + (size_t)t * 65536 + gm * 1024 + gc);
    pxr = nxr; pxz = nxz; pxe = nxe; pxh = nxh; ptm = ntm;
  }
  out[(size_t)TSTEPS * 65536 + gm * 1024 + gc] = hreg;
}

extern "C" void kernel_launch(void* const* d_in, const int* in_sizes, int n_in,
                              void* d_out, int out_size, void* d_ws, size_t ws_size,
                              hipStream_t stream) {
  const float* xs   = (const float*)d_in[0];
  const float* ms   = (const float*)d_in[1];
  const float* h0   = (const float*)d_in[2];
  const float* W_ih = (const float*)d_in[3];
  const float* b_ih = (const float*)d_in[4];
  const float* W_hh = (const float*)d_in[5];
  const float* b_hh = (const float*)d_in[6];
  const float* W_xh = (const float*)d_in[7];
  const float* b_xh = (const float*)d_in[8];
  const float* W_r  = (const float*)d_in[9];
  const float* b_r  = (const float*)d_in[10];

  char* ws = (char*)d_ws;
  size_t off = 0;
  _Float16* xs_h = (_Float16*)(ws + off); off += 67108864;   // [32768][1024] f16
  _Float16* wcat = (_Float16*)(ws + off); off += 8388608;    // [4096][1024] f16
  _Float16* whh  = (_Float16*)(ws + off); off += 6291456;    // [3072][1024] f16
  _Float16* wr   = (_Float16*)(ws + off); off += 2097152;    // [1024][1024] f16
  _Float16* xgh  = (_Float16*)(ws + off); off += 268435456;  // [32768][4096] f16
  _Float16* hx   = (_Float16*)(ws + off); off += 262144;     // [2][64][1024] f16 parity dbuf
  _Float16* rhx  = (_Float16*)(ws + off); off += 262144;     // [2][64][1024] f16 parity dbuf
  unsigned* ctr  = (unsigned*)(ws + off); off += 1024;       // 4 grp x 2 x 32 flags

  hipMemsetAsync(ctr, 0, 1024, stream);
  kconv<<<2048, 256, 0, stream>>>(xs, W_ih, W_xh, W_hh, W_r, h0,
                                  xs_h, wcat, whh, wr, hx);
  kgemm<<<dim3(32, 256), 256, 0, stream>>>(xs_h, wcat, b_ih, b_xh, xgh);
  krec<<<128, 512, 0, stream>>>(xgh, ms, whh, wr, b_hh, b_r, h0,
                                (u64*)hx, (u64*)rhx, (float*)d_out, ctr);
}